// Round 23
// baseline (324.866 us; speedup 1.0000x reference)
//
#include <hip/hip_runtime.h>
#include <hip/hip_bf16.h>
#include <stdint.h>

#define DK 4096
#define MROWS 8192
#define NOUT 4096
#define KP 4160            // 4096 + 31 lora cols + 33 zero pad; 65 tiles of 64
#define KP_B (KP*2)        // row stride in bytes for bf16 augmented buffers
#define NT 65              // K-tiles of 64

typedef __attribute__((ext_vector_type(8))) __bf16 bf16x8;
typedef __attribute__((ext_vector_type(4))) float f32x4;
typedef __attribute__((ext_vector_type(16))) float f32x16;
typedef unsigned short u16;

struct __align__(8) us4 { u16 x, y, z, w; };

__device__ __forceinline__ u16 f2bf(float f) {
  union { float f; uint32_t u; } v; v.f = f;
  uint32_t r = v.u + 0x7fffu + ((v.u >> 16) & 1u);
  return (u16)(r >> 16);
}

__device__ __forceinline__ void gload16(const void* g, void* l) {
  __builtin_amdgcn_global_load_lds(
      (const __attribute__((address_space(1))) unsigned int*)g,
      (__attribute__((address_space(3))) unsigned int*)l, 16, 0, 0);
}

// ---------------- prologue: build W_aug = [W ; coef_i * B_i] in bf16 ----------------
__global__ void build_W(const float* __restrict__ W,
                        const float* __restrict__ B16, const float* __restrict__ B8,
                        const float* __restrict__ B4,  const float* __restrict__ B2,
                        const float* __restrict__ B1,  const float* __restrict__ alphas,
                        u16* __restrict__ wb) {
  int n = blockIdx.x, t = threadIdx.x;
  const float* src = W + (size_t)n * DK;
  u16* dst = wb + (size_t)n * KP;
#pragma unroll
  for (int j = 0; j < 4; ++j) {
    int col = (t + j * 256) * 4;
    float4 v = *reinterpret_cast<const float4*>(src + col);
    us4 o = { f2bf(v.x), f2bf(v.y), f2bf(v.z), f2bf(v.w) };
    *reinterpret_cast<us4*>(dst + col) = o;
  }
  if (t < 64) {
    u16 val = 0;
    if (t < 31) {
      float coef; const float* Bp; int r, rl;
      if (t < 16)      { coef = alphas[0] * 4.0f;                Bp = B16; r = 16; rl = t; }
      else if (t < 24) { coef = alphas[1] * 5.656854249492381f;  Bp = B8;  r = 8;  rl = t - 16; }
      else if (t < 28) { coef = alphas[2] * 8.0f;                Bp = B4;  r = 4;  rl = t - 24; }
      else if (t < 30) { coef = alphas[3] * 11.313708498984761f; Bp = B2;  r = 2;  rl = t - 28; }
      else             { coef = alphas[4] * 16.0f;               Bp = B1;  r = 1;  rl = 0; }
      val = f2bf(coef * Bp[(size_t)n * r + rl]);
    }
    dst[4096 + t] = val;
  }
}

// ---------------- prologue: A_cat (31 rows + 1 zero row) -> bf16 [32][4096] ----------------
__global__ void build_A(const float* __restrict__ A16, const float* __restrict__ A8,
                        const float* __restrict__ A4,  const float* __restrict__ A2,
                        const float* __restrict__ A1,  u16* __restrict__ ab) {
  int rr = blockIdx.x, t = threadIdx.x;
  const float* src = nullptr;
  if (rr < 16)      src = A16 + (size_t)rr * DK;
  else if (rr < 24) src = A8 + (size_t)(rr - 16) * DK;
  else if (rr < 28) src = A4 + (size_t)(rr - 24) * DK;
  else if (rr < 30) src = A2 + (size_t)(rr - 28) * DK;
  else if (rr < 31) src = A1;
  u16* dst = ab + (size_t)rr * DK;
#pragma unroll
  for (int j = 0; j < 4; ++j) {
    int col = (t + j * 256) * 4;
    us4 o = { 0, 0, 0, 0 };
    if (src) {
      float4 v = *reinterpret_cast<const float4*>(src + col);
      o = { f2bf(v.x), f2bf(v.y), f2bf(v.z), f2bf(v.w) };
    }
    *reinterpret_cast<us4*>(dst + col) = o;
  }
}

// ---------------- fused: convert x -> xb AND xa = x @ A_cat^T (register-direct MFMA) ----------------
__global__ __launch_bounds__(256, 2) void conv_xa(const float* __restrict__ x, u16* __restrict__ xb,
                                                  const u16* __restrict__ ab) {
  __shared__ float part[4][2][64][4];  // 8 KB partial-xa combine
  int m0 = blockIdx.x * 16;
  int t = threadIdx.x, lane = t & 63, w = t >> 6;
  int l15 = lane & 15, lg = lane >> 4;
  int row = m0 + l15;
  const float* xp = x + (size_t)row * DK + w * 1024 + lg * 8;        // + kk*32
  u16* xbp = xb + (size_t)row * KP + w * 1024 + lg * 8;
  const u16* a0 = ab + (size_t)l15 * DK + w * 1024 + lg * 8;         // ni=0 rows
  const u16* a1 = ab + (size_t)(16 + l15) * DK + w * 1024 + lg * 8;  // ni=1 rows
  f32x4 acc0 = {}, acc1 = {};
  union { bf16x8 v; us4 h[2]; } xf;
#pragma unroll 4
  for (int kk = 0; kk < 32; ++kk) {
    float4 v0 = *reinterpret_cast<const float4*>(xp + kk * 32);
    float4 v1 = *reinterpret_cast<const float4*>(xp + kk * 32 + 4);
    xf.h[0] = us4{ f2bf(v0.x), f2bf(v0.y), f2bf(v0.z), f2bf(v0.w) };
    xf.h[1] = us4{ f2bf(v1.x), f2bf(v1.y), f2bf(v1.z), f2bf(v1.w) };
    *reinterpret_cast<us4*>(xbp + kk * 32) = xf.h[0];
    *reinterpret_cast<us4*>(xbp + kk * 32 + 4) = xf.h[1];
    bf16x8 af0 = *reinterpret_cast<const bf16x8*>(a0 + kk * 32);
    bf16x8 af1 = *reinterpret_cast<const bf16x8*>(a1 + kk * 32);
    acc0 = __builtin_amdgcn_mfma_f32_16x16x32_bf16(xf.v, af0, acc0, 0, 0, 0);
    acc1 = __builtin_amdgcn_mfma_f32_16x16x32_bf16(xf.v, af1, acc1, 0, 0, 0);
  }
  *reinterpret_cast<f32x4*>(&part[w][0][lane][0]) = acc0;
  *reinterpret_cast<f32x4*>(&part[w][1][lane][0]) = acc1;
  __syncthreads();
  if (w == 0) {
#pragma unroll
    for (int ni = 0; ni < 2; ++ni) {
      f32x4 s = *reinterpret_cast<const f32x4*>(&part[0][ni][lane][0]);
#pragma unroll
      for (int ww = 1; ww < 4; ++ww)
        s += *reinterpret_cast<const f32x4*>(&part[ww][ni][lane][0]);
#pragma unroll
      for (int r = 0; r < 4; ++r)   // C layout: col=l15, row=lg*4+r (verified)
        xb[(size_t)(m0 + lg * 4 + r) * KP + 4096 + ni * 16 + l15] = f2bf(s[r]);
    }
  }
  if (t < 128) {                    // zero pad cols 4128..4159 (16 rows x 32 cols)
    us4 z = { 0, 0, 0, 0 };
    *reinterpret_cast<us4*>(xb + (size_t)(m0 + (t >> 3)) * KP + 4128 + (t & 7) * 4) = z;
  }
}

// ---------------- main GEMM: 256x256, BK=64, 8 waves; 32x32x16 MFMA, counted-lgkm pipeline ----------------
// Same staging/sync as the verified 237us kernel; MFMA shape switched to 32x32x16 (+15% pipe
// ceiling, half the instruction count). LDS traffic identical. 4 ksteps of K=16 per tile:
//   S0: reads ks0 (6) | stage A(kt+1) x4
//   p0: reads ks1 (6) | stage B(kt+1) x4 | lgkm(6) | 8 MFMA ks0
//   p1: reads ks2 (6) | lgkm(6) | 8 MFMA ks1
//   p2: reads ks3 (6) | lgkm(6) | 8 MFMA ks2
//   p3: lgkm(0) | 8 MFMA ks3 | vmcnt(0) | BAR
// A-frag: lane holds A[row=lane&31][k=(lane>>5)*8..+8] (16B contiguous); B symmetric — any
// k-permutation error cancels (identical rule both operands). C/D mapping (m74/m101 verified):
// col=lane&31, row=(reg&3)+8*(reg>>2)+4*(lane>>5).
__device__ __forceinline__ void stage_tile(const char* gbase, char* lbase, int w, int lane, int i) {
  int chunk = (w << 2) + i;                       // 32 chunks of 1024 B cover 256 rows x 128 B
  int row = (chunk << 3) + (lane >> 3);
  int src_c = ((lane & 7) ^ (lane >> 3)) << 4;    // (l&7)*16 ^ ((row&7)<<4)
  gload16(gbase + (size_t)row * KP_B + src_c, lbase + chunk * 1024);
}

__device__ __forceinline__ bf16x8 rdfrag(const char* base, int row, int cb) {
  return *reinterpret_cast<const bf16x8*>(base + row * 128 + (cb ^ ((row & 7) << 4)));
}

__global__ __launch_bounds__(512, 2) void gemm_main(const u16* __restrict__ xb, const u16* __restrict__ wb,
                                                    const float* __restrict__ bias, float* __restrict__ out) {
  __shared__ u16 As0[256 * 64], As1[256 * 64];   // 32 KB each
  __shared__ u16 Bs0[256 * 64], Bs1[256 * 64];   // total 128 KB
  int bid = blockIdx.x;
  int swz = (bid & 7) * 64 + (bid >> 3);         // 512 blocks, 512%8==0 -> bijective XCD swizzle
  int mt = swz >> 4, nt = swz & 15;              // 32 x 16 tiles
  int m0 = mt * 256, n0 = nt * 256;
  int t = threadIdx.x, lane = t & 63, w = t >> 6;
  int wr = w >> 2, wc = w & 3;                   // 2 x 4 waves; per-wave out 128 x 64
  int l31 = lane & 31, lh = lane >> 5;           // 32-row index, k-half

  f32x16 acc[4][2] = {};
  bf16x8 fa0[4], fa1[4], fb0[2], fb1[2];

  const char* Ag = (const char*)xb + (size_t)m0 * KP_B;
  const char* Bg = (const char*)wb + (size_t)n0 * KP_B;
  char *AcA = (char*)As0, *AnA = (char*)As1, *AcB = (char*)Bs0, *AnB = (char*)Bs1;

  // prologue: stage A(0),B(0) into bufs0, drain, barrier
#pragma unroll
  for (int i = 0; i < 4; ++i) stage_tile(Ag, AcA, w, lane, i);
#pragma unroll
  for (int i = 0; i < 4; ++i) stage_tile(Bg, AcB, w, lane, i);
  asm volatile("s_waitcnt vmcnt(0)" ::: "memory");
  __builtin_amdgcn_s_barrier();

  const int Arow = wr * 128 + l31;               // + mi*32
  const int Brow = wc * 64 + l31;                // + ni*32
  const int cb0 = lh * 16;                       // + ks*32

  for (int kt = 0; kt < NT; ++kt) {
    const char* Agk1 = Ag + (size_t)(kt + 1) * 128;
    const char* Bgk1 = Bg + (size_t)(kt + 1) * 128;
    const bool doS = (kt + 1 < NT);

    // -------- S0: ks0 reads | stage A(kt+1) x4
#pragma unroll
    for (int mi = 0; mi < 4; ++mi) fa0[mi] = rdfrag(AcA, Arow + mi * 32, cb0);
#pragma unroll
    for (int ni = 0; ni < 2; ++ni) fb0[ni] = rdfrag(AcB, Brow + ni * 32, cb0);
    if (doS) {
      stage_tile(Agk1, AnA, w, lane, 0); stage_tile(Agk1, AnA, w, lane, 1);
      stage_tile(Agk1, AnA, w, lane, 2); stage_tile(Agk1, AnA, w, lane, 3);
    }

    // -------- p0: ks1 reads | stage B(kt+1) x4 | lgkm(6) | 8 MFMA ks0
#pragma unroll
    for (int mi = 0; mi < 4; ++mi) fa1[mi] = rdfrag(AcA, Arow + mi * 32, cb0 + 32);
#pragma unroll
    for (int ni = 0; ni < 2; ++ni) fb1[ni] = rdfrag(AcB, Brow + ni * 32, cb0 + 32);
    if (doS) {
      stage_tile(Bgk1, AnB, w, lane, 0); stage_tile(Bgk1, AnB, w, lane, 1);
      stage_tile(Bgk1, AnB, w, lane, 2); stage_tile(Bgk1, AnB, w, lane, 3);
    }
    asm volatile("s_waitcnt lgkmcnt(6)" ::: "memory");   // ks0 drained; ks1 may fly
    __builtin_amdgcn_sched_barrier(0);
    __builtin_amdgcn_s_setprio(1);
#pragma unroll
    for (int mi = 0; mi < 4; ++mi)
#pragma unroll
      for (int ni = 0; ni < 2; ++ni)
        acc[mi][ni] = __builtin_amdgcn_mfma_f32_32x32x16_bf16(fa0[mi], fb0[ni], acc[mi][ni], 0, 0, 0);
    __builtin_amdgcn_s_setprio(0);

    // -------- p1: ks2 reads (reuse fa0/fb0) | lgkm(6) | 8 MFMA ks1
#pragma unroll
    for (int mi = 0; mi < 4; ++mi) fa0[mi] = rdfrag(AcA, Arow + mi * 32, cb0 + 64);
#pragma unroll
    for (int ni = 0; ni < 2; ++ni) fb0[ni] = rdfrag(AcB, Brow + ni * 32, cb0 + 64);
    asm volatile("s_waitcnt lgkmcnt(6)" ::: "memory");   // ks1 drained; ks2 may fly
    __builtin_amdgcn_sched_barrier(0);
    __builtin_amdgcn_s_setprio(1);
#pragma unroll
    for (int mi = 0; mi < 4; ++mi)
#pragma unroll
      for (int ni = 0; ni < 2; ++ni)
        acc[mi][ni] = __builtin_amdgcn_mfma_f32_32x32x16_bf16(fa1[mi], fb1[ni], acc[mi][ni], 0, 0, 0);
    __builtin_amdgcn_s_setprio(0);

    // -------- p2: ks3 reads (reuse fa1/fb1) | lgkm(6) | 8 MFMA ks2
#pragma unroll
    for (int mi = 0; mi < 4; ++mi) fa1[mi] = rdfrag(AcA, Arow + mi * 32, cb0 + 96);
#pragma unroll
    for (int ni = 0; ni < 2; ++ni) fb1[ni] = rdfrag(AcB, Brow + ni * 32, cb0 + 96);
    asm volatile("s_waitcnt lgkmcnt(6)" ::: "memory");   // ks2 drained; ks3 may fly
    __builtin_amdgcn_sched_barrier(0);
    __builtin_amdgcn_s_setprio(1);
#pragma unroll
    for (int mi = 0; mi < 4; ++mi)
#pragma unroll
      for (int ni = 0; ni < 2; ++ni)
        acc[mi][ni] = __builtin_amdgcn_mfma_f32_32x32x16_bf16(fa0[mi], fb0[ni], acc[mi][ni], 0, 0, 0);
    __builtin_amdgcn_s_setprio(0);

    // -------- p3: lgkm(0) | 8 MFMA ks3 | vmcnt(0) | BAR
    asm volatile("s_waitcnt lgkmcnt(0)" ::: "memory");   // ks3 drained (covered by p2 MFMA)
    __builtin_amdgcn_sched_barrier(0);
    __builtin_amdgcn_s_setprio(1);
#pragma unroll
    for (int mi = 0; mi < 4; ++mi)
#pragma unroll
      for (int ni = 0; ni < 2; ++ni)
        acc[mi][ni] = __builtin_amdgcn_mfma_f32_32x32x16_bf16(fa1[mi], fb1[ni], acc[mi][ni], 0, 0, 0);
    __builtin_amdgcn_s_setprio(0);
    asm volatile("s_waitcnt vmcnt(0)" ::: "memory");     // kt+1 tiles landed (issued in S0/p0)
    __builtin_amdgcn_s_barrier();

    { char* tp = AcA; AcA = AnA; AnA = tp; }
    { char* tp = AcB; AcB = AnB; AnB = tp; }
  }

  // ---------------- epilogue: bias + store (32x32 C/D: col=lane&31, row=(r&3)+8*(r>>2)+4*lh) ----
  float bn[2];
#pragma unroll
  for (int ni = 0; ni < 2; ++ni) bn[ni] = bias[n0 + wc * 64 + ni * 32 + l31];
#pragma unroll
  for (int mi = 0; mi < 4; ++mi) {
    int rbase = m0 + wr * 128 + mi * 32 + 4 * lh;
#pragma unroll
    for (int ni = 0; ni < 2; ++ni) {
      int n = n0 + wc * 64 + ni * 32 + l31;
#pragma unroll
      for (int r = 0; r < 16; ++r) {
        int row = rbase + (r & 3) + 8 * (r >> 2);
        out[(size_t)row * NOUT + n] = acc[mi][ni][r] + bn[ni];
      }
    }
  }
}

extern "C" void kernel_launch(void* const* d_in, const int* in_sizes, int n_in,
                              void* d_out, int out_size, void* d_ws, size_t ws_size,
                              hipStream_t stream) {
  const float* x   = (const float*)d_in[0];
  const float* W   = (const float*)d_in[1];
  const float* b   = (const float*)d_in[2];
  const float* A16 = (const float*)d_in[3];
  const float* B16 = (const float*)d_in[4];
  const float* A8  = (const float*)d_in[5];
  const float* B8  = (const float*)d_in[6];
  const float* A4  = (const float*)d_in[7];
  const float* B4  = (const float*)d_in[8];
  const float* A2  = (const float*)d_in[9];
  const float* B2  = (const float*)d_in[10];
  const float* A1  = (const float*)d_in[11];
  const float* B1  = (const float*)d_in[12];
  const float* alphas = (const float*)d_in[13];

  char* ws = (char*)d_ws;
  u16* xb = (u16*)ws;                                   // 8192*4160*2 = 68,157,440 B
  u16* wb = (u16*)(ws + 68157440);                      // 4096*4160*2 = 34,078,720 B
  u16* ab = (u16*)(ws + 68157440 + 34078720);           // 32*4096*2   =    262,144 B
  float* out = (float*)d_out;

  build_A<<<32, 256, 0, stream>>>(A16, A8, A4, A2, A1, ab);
  conv_xa<<<MROWS / 16, 256, 0, stream>>>(x, xb, ab);
  build_W<<<NOUT, 256, 0, stream>>>(W, B16, B8, B4, B2, B1, alphas, wb);
  gemm_main<<<(MROWS / 256) * (NOUT / 256), 512, 0, stream>>>(xb, wb, b, out);
}

// Round 24
// 293.576 us; speedup vs baseline: 1.1066x; 1.1066x over previous
//
#include <hip/hip_runtime.h>
#include <hip/hip_bf16.h>
#include <stdint.h>

#define DK 4096
#define MROWS 8192
#define NOUT 4096
#define KP 4160            // 4096 + 31 lora cols + 33 zero pad; 65 tiles of 64
#define KP_B (KP*2)        // row stride in bytes for bf16 augmented buffers
#define NT 65              // K-tiles of 64

typedef __attribute__((ext_vector_type(8))) __bf16 bf16x8;
typedef __attribute__((ext_vector_type(4))) float f32x4;
typedef unsigned short u16;

struct __align__(8) us4 { u16 x, y, z, w; };

__device__ __forceinline__ u16 f2bf(float f) {
  union { float f; uint32_t u; } v; v.f = f;
  uint32_t r = v.u + 0x7fffu + ((v.u >> 16) & 1u);
  return (u16)(r >> 16);
}

__device__ __forceinline__ void gload16(const void* g, void* l) {
  __builtin_amdgcn_global_load_lds(
      (const __attribute__((address_space(1))) unsigned int*)g,
      (__attribute__((address_space(3))) unsigned int*)l, 16, 0, 0);
}

// ---------------- prologue: build W_aug = [W ; coef_i * B_i] in bf16 ----------------
__global__ void build_W(const float* __restrict__ W,
                        const float* __restrict__ B16, const float* __restrict__ B8,
                        const float* __restrict__ B4,  const float* __restrict__ B2,
                        const float* __restrict__ B1,  const float* __restrict__ alphas,
                        u16* __restrict__ wb) {
  int n = blockIdx.x, t = threadIdx.x;
  const float* src = W + (size_t)n * DK;
  u16* dst = wb + (size_t)n * KP;
#pragma unroll
  for (int j = 0; j < 4; ++j) {
    int col = (t + j * 256) * 4;
    float4 v = *reinterpret_cast<const float4*>(src + col);
    us4 o = { f2bf(v.x), f2bf(v.y), f2bf(v.z), f2bf(v.w) };
    *reinterpret_cast<us4*>(dst + col) = o;
  }
  if (t < 64) {
    u16 val = 0;
    if (t < 31) {
      float coef; const float* Bp; int r, rl;
      if (t < 16)      { coef = alphas[0] * 4.0f;                Bp = B16; r = 16; rl = t; }
      else if (t < 24) { coef = alphas[1] * 5.656854249492381f;  Bp = B8;  r = 8;  rl = t - 16; }
      else if (t < 28) { coef = alphas[2] * 8.0f;                Bp = B4;  r = 4;  rl = t - 24; }
      else if (t < 30) { coef = alphas[3] * 11.313708498984761f; Bp = B2;  r = 2;  rl = t - 28; }
      else             { coef = alphas[4] * 16.0f;               Bp = B1;  r = 1;  rl = 0; }
      val = f2bf(coef * Bp[(size_t)n * r + rl]);
    }
    dst[4096 + t] = val;
  }
}

// ---------------- prologue: A_cat (31 rows + 1 zero row) -> bf16 [32][4096] ----------------
__global__ void build_A(const float* __restrict__ A16, const float* __restrict__ A8,
                        const float* __restrict__ A4,  const float* __restrict__ A2,
                        const float* __restrict__ A1,  u16* __restrict__ ab) {
  int rr = blockIdx.x, t = threadIdx.x;
  const float* src = nullptr;
  if (rr < 16)      src = A16 + (size_t)rr * DK;
  else if (rr < 24) src = A8 + (size_t)(rr - 16) * DK;
  else if (rr < 28) src = A4 + (size_t)(rr - 24) * DK;
  else if (rr < 30) src = A2 + (size_t)(rr - 28) * DK;
  else if (rr < 31) src = A1;
  u16* dst = ab + (size_t)rr * DK;
#pragma unroll
  for (int j = 0; j < 4; ++j) {
    int col = (t + j * 256) * 4;
    us4 o = { 0, 0, 0, 0 };
    if (src) {
      float4 v = *reinterpret_cast<const float4*>(src + col);
      o = { f2bf(v.x), f2bf(v.y), f2bf(v.z), f2bf(v.w) };
    }
    *reinterpret_cast<us4*>(dst + col) = o;
  }
}

// ---------------- fused: convert x -> xb AND xa = x @ A_cat^T (register-direct MFMA) ----------------
__global__ __launch_bounds__(256, 2) void conv_xa(const float* __restrict__ x, u16* __restrict__ xb,
                                                  const u16* __restrict__ ab) {
  __shared__ float part[4][2][64][4];  // 8 KB partial-xa combine
  int m0 = blockIdx.x * 16;
  int t = threadIdx.x, lane = t & 63, w = t >> 6;
  int l15 = lane & 15, lg = lane >> 4;
  int row = m0 + l15;
  const float* xp = x + (size_t)row * DK + w * 1024 + lg * 8;        // + kk*32
  u16* xbp = xb + (size_t)row * KP + w * 1024 + lg * 8;
  const u16* a0 = ab + (size_t)l15 * DK + w * 1024 + lg * 8;         // ni=0 rows
  const u16* a1 = ab + (size_t)(16 + l15) * DK + w * 1024 + lg * 8;  // ni=1 rows
  f32x4 acc0 = {}, acc1 = {};
  union { bf16x8 v; us4 h[2]; } xf;
#pragma unroll 4
  for (int kk = 0; kk < 32; ++kk) {
    float4 v0 = *reinterpret_cast<const float4*>(xp + kk * 32);
    float4 v1 = *reinterpret_cast<const float4*>(xp + kk * 32 + 4);
    xf.h[0] = us4{ f2bf(v0.x), f2bf(v0.y), f2bf(v0.z), f2bf(v0.w) };
    xf.h[1] = us4{ f2bf(v1.x), f2bf(v1.y), f2bf(v1.z), f2bf(v1.w) };
    *reinterpret_cast<us4*>(xbp + kk * 32) = xf.h[0];
    *reinterpret_cast<us4*>(xbp + kk * 32 + 4) = xf.h[1];
    bf16x8 af0 = *reinterpret_cast<const bf16x8*>(a0 + kk * 32);
    bf16x8 af1 = *reinterpret_cast<const bf16x8*>(a1 + kk * 32);
    acc0 = __builtin_amdgcn_mfma_f32_16x16x32_bf16(xf.v, af0, acc0, 0, 0, 0);
    acc1 = __builtin_amdgcn_mfma_f32_16x16x32_bf16(xf.v, af1, acc1, 0, 0, 0);
  }
  *reinterpret_cast<f32x4*>(&part[w][0][lane][0]) = acc0;
  *reinterpret_cast<f32x4*>(&part[w][1][lane][0]) = acc1;
  __syncthreads();
  if (w == 0) {
#pragma unroll
    for (int ni = 0; ni < 2; ++ni) {
      f32x4 s = *reinterpret_cast<const f32x4*>(&part[0][ni][lane][0]);
#pragma unroll
      for (int ww = 1; ww < 4; ++ww)
        s += *reinterpret_cast<const f32x4*>(&part[ww][ni][lane][0]);
#pragma unroll
      for (int r = 0; r < 4; ++r)   // C layout: col=l15, row=lg*4+r (verified)
        xb[(size_t)(m0 + lg * 4 + r) * KP + 4096 + ni * 16 + l15] = f2bf(s[r]);
    }
  }
  if (t < 128) {                    // zero pad cols 4128..4159 (16 rows x 32 cols)
    us4 z = { 0, 0, 0, 0 };
    *reinterpret_cast<us4*>(xb + (size_t)(m0 + (t >> 3)) * KP + 4128 + (t & 7) * 4) = z;
  }
}

// ---------------- main GEMM: 256x256, BK=64, 8 waves, counted-lgkm pipeline (verified 233-237us) ----
// One barrier + one vmcnt per K-tile. Both A(kt+1),B(kt+1) stage into the ALTERNATE buffers
// (read buf = bufs[kt&1]) -> no mid-tile overwrite hazard. Fragment reads for phase p+1 issue
// BEFORE phase p's MFMA; counted lgkm waits (DS is FIFO) let them fly under the MFMA clusters.
__device__ __forceinline__ void stage_tile(const char* gbase, char* lbase, int w, int lane, int i) {
  int chunk = (w << 2) + i;                       // 32 chunks of 1024 B cover 256 rows x 128 B
  int row = (chunk << 3) + (lane >> 3);
  int src_c = ((lane & 7) ^ (lane >> 3)) << 4;    // (l&7)*16 ^ ((row&7)<<4)
  gload16(gbase + (size_t)row * KP_B + src_c, lbase + chunk * 1024);
}

__device__ __forceinline__ bf16x8 rdfrag(const char* base, int row, int cb) {
  return *reinterpret_cast<const bf16x8*>(base + row * 128 + (cb ^ ((row & 7) << 4)));
}

__global__ __launch_bounds__(512, 2) void gemm_main(const u16* __restrict__ xb, const u16* __restrict__ wb,
                                                    const float* __restrict__ bias, float* __restrict__ out) {
  __shared__ u16 As0[256 * 64], As1[256 * 64];   // 32 KB each
  __shared__ u16 Bs0[256 * 64], Bs1[256 * 64];   // total 128 KB
  int bid = blockIdx.x;
  int swz = (bid & 7) * 64 + (bid >> 3);         // 512 blocks, 512%8==0 -> bijective XCD swizzle
  int mt = swz >> 4, nt = swz & 15;              // 32 x 16 tiles
  int m0 = mt * 256, n0 = nt * 256;
  int t = threadIdx.x, lane = t & 63, w = t >> 6;
  int wr = w >> 2, wc = w & 3;                   // 2 x 4 waves; per-wave out 128 x 64
  int l15 = lane & 15, lg = lane >> 4;

  f32x4 acc[8][4] = {};
  bf16x8 af[4][2], af2[4][2], bl[2][2], bh[2][2];

  const char* Ag = (const char*)xb + (size_t)m0 * KP_B;
  const char* Bg = (const char*)wb + (size_t)n0 * KP_B;
  char *AcA = (char*)As0, *AnA = (char*)As1, *AcB = (char*)Bs0, *AnB = (char*)Bs1;

  // prologue: stage A(0),B(0) into bufs0, drain, barrier
#pragma unroll
  for (int i = 0; i < 4; ++i) stage_tile(Ag, AcA, w, lane, i);
#pragma unroll
  for (int i = 0; i < 4; ++i) stage_tile(Bg, AcB, w, lane, i);
  asm volatile("s_waitcnt vmcnt(0)" ::: "memory");
  __builtin_amdgcn_s_barrier();

  const int Arow = wr * 128 + l15;               // + mh*64 + mi*16
  const int Brow = wc * 64 + l15;                // + nh*32 + ni*16
  const int cb0 = lg * 16;                       // + ks*64

  for (int kt = 0; kt < NT; ++kt) {
    const char* Agk1 = Ag + (size_t)(kt + 1) * 128;
    const char* Bgk1 = Bg + (size_t)(kt + 1) * 128;
    const bool doS = (kt + 1 < NT);

    // -------- S0: af-lo + bl reads | stage A(kt+1) x4
#pragma unroll
    for (int mi = 0; mi < 4; ++mi)
#pragma unroll
      for (int ks = 0; ks < 2; ++ks)
        af[mi][ks] = rdfrag(AcA, Arow + mi * 16, cb0 + ks * 64);
#pragma unroll
    for (int ni = 0; ni < 2; ++ni)
#pragma unroll
      for (int ks = 0; ks < 2; ++ks)
        bl[ni][ks] = rdfrag(AcB, Brow + ni * 16, cb0 + ks * 64);
    if (doS) {
      stage_tile(Agk1, AnA, w, lane, 0); stage_tile(Agk1, AnA, w, lane, 1);
      stage_tile(Agk1, AnA, w, lane, 2); stage_tile(Agk1, AnA, w, lane, 3);
    }

    // -------- p0: bh reads | stage B(kt+1) x4 | lgkm(4) | MFMA af*bl
#pragma unroll
    for (int ni = 0; ni < 2; ++ni)
#pragma unroll
      for (int ks = 0; ks < 2; ++ks)
        bh[ni][ks] = rdfrag(AcB, Brow + 32 + ni * 16, cb0 + ks * 64);
    if (doS) {
      stage_tile(Bgk1, AnB, w, lane, 0); stage_tile(Bgk1, AnB, w, lane, 1);
      stage_tile(Bgk1, AnB, w, lane, 2); stage_tile(Bgk1, AnB, w, lane, 3);
    }
    asm volatile("s_waitcnt lgkmcnt(4)" ::: "memory");   // S0 (12 reads) drained; bh may fly
    __builtin_amdgcn_sched_barrier(0);
    __builtin_amdgcn_s_setprio(1);
#pragma unroll
    for (int mi = 0; mi < 4; ++mi)
#pragma unroll
      for (int ni = 0; ni < 2; ++ni)
#pragma unroll
        for (int ks = 0; ks < 2; ++ks)
          acc[mi][ni] = __builtin_amdgcn_mfma_f32_16x16x32_bf16(af[mi][ks], bl[ni][ks], acc[mi][ni], 0, 0, 0);
    __builtin_amdgcn_s_setprio(0);

    // -------- p1: af2 reads | lgkm(8) | MFMA af*bh
#pragma unroll
    for (int mi = 0; mi < 4; ++mi)
#pragma unroll
      for (int ks = 0; ks < 2; ++ks)
        af2[mi][ks] = rdfrag(AcA, Arow + 64 + mi * 16, cb0 + ks * 64);
    asm volatile("s_waitcnt lgkmcnt(8)" ::: "memory");   // bh drained; af2 (8) may fly
    __builtin_amdgcn_sched_barrier(0);
    __builtin_amdgcn_s_setprio(1);
#pragma unroll
    for (int mi = 0; mi < 4; ++mi)
#pragma unroll
      for (int ni = 0; ni < 2; ++ni)
#pragma unroll
        for (int ks = 0; ks < 2; ++ks)
          acc[mi][ni + 2] = __builtin_amdgcn_mfma_f32_16x16x32_bf16(af[mi][ks], bh[ni][ks], acc[mi][ni + 2], 0, 0, 0);
    __builtin_amdgcn_s_setprio(0);

    // -------- p2: lgkm(0) | MFMA af2*bh
    asm volatile("s_waitcnt lgkmcnt(0)" ::: "memory");   // af2 drained (covered by p1 MFMA)
    __builtin_amdgcn_sched_barrier(0);
    __builtin_amdgcn_s_setprio(1);
#pragma unroll
    for (int mi = 0; mi < 4; ++mi)
#pragma unroll
      for (int ni = 0; ni < 2; ++ni)
#pragma unroll
        for (int ks = 0; ks < 2; ++ks)
          acc[mi + 4][ni + 2] = __builtin_amdgcn_mfma_f32_16x16x32_bf16(af2[mi][ks], bh[ni][ks], acc[mi + 4][ni + 2], 0, 0, 0);
    __builtin_amdgcn_s_setprio(0);

    // -------- p3: MFMA af2*bl | vmcnt(0) | BAR
    __builtin_amdgcn_s_setprio(1);
#pragma unroll
    for (int mi = 0; mi < 4; ++mi)
#pragma unroll
      for (int ni = 0; ni < 2; ++ni)
#pragma unroll
        for (int ks = 0; ks < 2; ++ks)
          acc[mi + 4][ni] = __builtin_amdgcn_mfma_f32_16x16x32_bf16(af2[mi][ks], bl[ni][ks], acc[mi + 4][ni], 0, 0, 0);
    __builtin_amdgcn_s_setprio(0);
    asm volatile("s_waitcnt vmcnt(0)" ::: "memory");     // kt+1 tiles landed (issued in S0/p0)
    __builtin_amdgcn_s_barrier();

    { char* tp = AcA; AcA = AnA; AnA = tp; }
    { char* tp = AcB; AcB = AnB; AnB = tp; }
  }

  // ---------------- epilogue: bias + store ----------------
  float bn[4];
#pragma unroll
  for (int ni = 0; ni < 4; ++ni) bn[ni] = bias[n0 + wc * 64 + ni * 16 + l15];
#pragma unroll
  for (int mi = 0; mi < 8; ++mi) {
    int mbase = m0 + wr * 128 + mi * 16 + lg * 4;
#pragma unroll
    for (int ni = 0; ni < 4; ++ni) {
      int n = n0 + wc * 64 + ni * 16 + l15;
#pragma unroll
      for (int r = 0; r < 4; ++r)
        out[(size_t)(mbase + r) * NOUT + n] = acc[mi][ni][r] + bn[ni];
    }
  }
}

extern "C" void kernel_launch(void* const* d_in, const int* in_sizes, int n_in,
                              void* d_out, int out_size, void* d_ws, size_t ws_size,
                              hipStream_t stream) {
  const float* x   = (const float*)d_in[0];
  const float* W   = (const float*)d_in[1];
  const float* b   = (const float*)d_in[2];
  const float* A16 = (const float*)d_in[3];
  const float* B16 = (const float*)d_in[4];
  const float* A8  = (const float*)d_in[5];
  const float* B8  = (const float*)d_in[6];
  const float* A4  = (const float*)d_in[7];
  const float* B4  = (const float*)d_in[8];
  const float* A2  = (const float*)d_in[9];
  const float* B2  = (const float*)d_in[10];
  const float* A1  = (const float*)d_in[11];
  const float* B1  = (const float*)d_in[12];
  const float* alphas = (const float*)d_in[13];

  char* ws = (char*)d_ws;
  u16* xb = (u16*)ws;                                   // 8192*4160*2 = 68,157,440 B
  u16* wb = (u16*)(ws + 68157440);                      // 4096*4160*2 = 34,078,720 B
  u16* ab = (u16*)(ws + 68157440 + 34078720);           // 32*4096*2   =    262,144 B
  float* out = (float*)d_out;

  build_A<<<32, 256, 0, stream>>>(A16, A8, A4, A2, A1, ab);
  conv_xa<<<MROWS / 16, 256, 0, stream>>>(x, xb, ab);
  build_W<<<NOUT, 256, 0, stream>>>(W, B16, B8, B4, B2, B1, alphas, wb);
  gemm_main<<<(MROWS / 256) * (NOUT / 256), 512, 0, stream>>>(xb, wb, b, out);
}